// Round 7
// baseline (807.413 us; speedup 1.0000x reference)
//
#include <hip/hip_runtime.h>

#define TT 2048
#define BB 128
#define II 32
#define HH 128
#define NW (TT / 8)

typedef float v2f __attribute__((ext_vector_type(2)));
typedef float v4f __attribute__((ext_vector_type(4)));
typedef unsigned int u32;
typedef __attribute__((address_space(3))) u32 lds_u32;
typedef const __attribute__((address_space(1))) u32 glb_u32;

// packed dual fp32 FMA (VOP3P)
__device__ __forceinline__ v2f pk_fma(v2f a, v2f b, v2f c) {
    v2f d;
    asm("v_pk_fma_f32 %0, %1, %2, %3" : "=v"(d) : "v"(a), "v"(b), "v"(c));
    return d;
}

// DPP ctrl: 0xB1 quad xor1, 0x4E quad xor2,
// 0x104 row_shl:4 (lane i <- i+4), 0x114 row_shr:4 (lane i <- i-4),
// 0x128 row_ror:8 (== xor8 within 16 lanes)
template <int CTRL>
__device__ __forceinline__ float dpp_mov(float p) {
    return __int_as_float(__builtin_amdgcn_update_dpp(0, __float_as_int(p), CTRL, 0xF, 0xF, true));
}
template <int CTRL>
__device__ __forceinline__ float dpp_add(float p) {
    return p + dpp_mov<CTRL>(p);
}
template <int CTRL>
__device__ __forceinline__ float pair_red(float x, float y, bool sel) {
    float keep = sel ? y : x;
    float give = sel ? x : y;
    return keep + dpp_mov<CTRL>(give);
}

// 4 waves x 64 lanes, one block per batch element, 1 wave/SIMD.
// Same skeleton as R6 (rows 8/group, DPP reduce-scatter, single LDS h hop,
// lgkm-only barrier). Deltas: weights prescaled by 2*log2(e) (tanh mul off
// path); blend via persistent hpre=(1-a)h (1 fma on path); V(t-2) computed
// in the h-read latency shadow from previous step's registers and stored to
// an LDS vres buffer (no global stores / vmcnt pollution in the loop),
// flushed at kernel end.
__global__ __launch_bounds__(256)
void vrnn_kernel(const float* __restrict__ X, const float* __restrict__ W_in,
                 const float* __restrict__ W_hh, const float* __restrict__ rnn_bias,
                 const float* __restrict__ alpha, const float* __restrict__ value_W,
                 const float* __restrict__ value_bias, float* __restrict__ out)
{
    const int b    = blockIdx.x;
    const int tid  = threadIdx.x;
    const int wave = tid >> 6;        // 0..3
    const int lane = tid & 63;
    const int g    = lane >> 4;       // 0..3
    const int j    = lane & 15;       // 0..15
    const int base = 32 * wave + 8 * g;
    const int rown = base + (j & 7);

    __shared__ __align__(16) float xw[2][8][II];     // 2 KB X windows
    __shared__ __align__(16) float hbuf[2][192];     // 16 chunks x 12 floats
    __shared__ __align__(16) float vres[TT];         // 8 KB V staging

    // ---- stage window 0 early ----
    if (wave == 0) {
        const float* src = X + (size_t)(lane >> 3) * (BB * II) + b * II + (lane & 7) * 4;
        __builtin_amdgcn_global_load_lds((glb_u32*)src, (lds_u32*)(&xw[0][0][0]), 16, 0, 0);
    }

    const float SC = 2.8853900817779268f;   // 2*log2(e): prescale so e=exp2(pre)

    // ---- per-lane constants (prescaled) ----
    v2f wh[8][4], wi8[8], binit[8];
#pragma unroll
    for (int r = 0; r < 8; ++r) {
        const float* wr = W_hh + (size_t)(base + r) * HH + 8 * j;
        v4f a0 = *(const v4f*)(wr);
        v4f a1 = *(const v4f*)(wr + 4);
        wh[r][0] = (v2f){a0.x * SC, a0.y * SC}; wh[r][1] = (v2f){a0.z * SC, a0.w * SC};
        wh[r][2] = (v2f){a1.x * SC, a1.y * SC}; wh[r][3] = (v2f){a1.z * SC, a1.w * SC};
        v2f wiv  = *(const v2f*)(W_in + (size_t)(base + r) * II + 2 * j);
        wi8[r]   = (v2f){wiv.x * SC, wiv.y * SC};
        binit[r] = (v2f){ (j == 0) ? rnn_bias[base + r] * SC : 0.0f, 0.0f };
    }
    v2f vwc[4];
#pragma unroll
    for (int i = 0; i < 4; ++i) vwc[i] = *(const v2f*)(value_W + 8 * j + 2 * i);
    const float al_own = alpha[rown];
    const float vb     = value_bias[0];
    const bool  b0 = (j & 1) != 0;
    const bool  b1 = (j & 2) != 0;
    const bool  b2 = (j & 4) != 0;
    const int   woff = 12 * (4 * wave + g) + (j & 7);
    float hreg = 0.0f;
    float hpre = 0.0f;                                  // (1-al)*hreg, maintained in slack
    v2f hpPrev[4] = { (v2f){0,0}, (v2f){0,0}, (v2f){0,0}, (v2f){0,0} };

    if (tid < 192) hbuf[1][tid] = 0.0f;                 // h_{-1} = 0
    __syncthreads();

    float* outV = out;
    float* outH = out + (size_t)TT * BB;

    for (int w = 0; w < NW; ++w) {
        if (wave == 0 && w + 1 < NW) {
            const float* src = X + (size_t)((w + 1) * 8 + (lane >> 3)) * (BB * II)
                                 + b * II + (lane & 7) * 4;
            __builtin_amdgcn_global_load_lds((glb_u32*)src,
                (lds_u32*)(&xw[(w + 1) & 1][0][0]), 16, 0, 0);
        }
#pragma unroll
        for (int s = 0; s < 8; ++s) {
            const int par = s & 1;                      // t&1 (t = 8w+s)
            const int t   = 8 * w + s;
            // ---- issue h_{t-1} chunk read + x pair read FIRST ----
            const float* hb = &hbuf[par ^ 1][12 * j];
            const v4f h0 = *(const v4f*)(hb);
            const v4f h1 = *(const v4f*)(hb + 4);
            const v2f xc = *(const v2f*)(&xw[w & 1][s][2 * j]);
            // ---- SHADOW: V_{t-2} from hpPrev (h_{t-2}) on rotating wave ----
            if (wave == ((s + 2) & 3) && t >= 2) {
                v2f vt = vwc[0] * hpPrev[0];
                vt = pk_fma(vwc[1], hpPrev[1], vt);
                vt = pk_fma(vwc[2], hpPrev[2], vt);
                vt = pk_fma(vwc[3], hpPrev[3], vt);
                float vs = vt.x + vt.y;
                vs = dpp_add<0xB1>(vs);
                vs = dpp_add<0x4E>(vs);
                const float uL = dpp_mov<0x104>(vs);  // lane i <- i+4
                const float uR = dpp_mov<0x114>(vs);  // lane i <- i-4
                vs += b2 ? uR : uL;
                vs = dpp_add<0x128>(vs);
                if (lane == 0) vres[t - 2] = vb + vs;
            }
            v2f hp[4] = { (v2f){h0.x, h0.y}, (v2f){h0.z, h0.w},
                          (v2f){h1.x, h1.y}, (v2f){h1.z, h1.w} };
            // ---- 8 row-partials: 5-deep pk_fma chains ----
            float p[8];
#pragma unroll
            for (int r = 0; r < 8; ++r) {
                v2f a = pk_fma(wi8[r], xc, binit[r]);
                a = pk_fma(wh[r][0], hp[0], a);
                a = pk_fma(wh[r][1], hp[1], a);
                a = pk_fma(wh[r][2], hp[2], a);
                a = pk_fma(wh[r][3], hp[3], a);
                p[r] = a.x + a.y;
            }
            // ---- reduce-scatter 8 rows over 16 lanes ----
            float q0 = pair_red<0xB1>(p[0], p[1], b0);
            float q1 = pair_red<0xB1>(p[2], p[3], b0);
            float q2 = pair_red<0xB1>(p[4], p[5], b0);
            float q3 = pair_red<0xB1>(p[6], p[7], b0);
            float r0 = pair_red<0x4E>(q0, q1, b1);
            float r1 = pair_red<0x4E>(q2, q3, b1);
            const float k3  = b2 ? r1 : r0;
            const float g3  = b2 ? r0 : r1;
            const float vL  = dpp_mov<0x104>(g3);   // lane i <- i+4
            const float vR  = dpp_mov<0x114>(g3);   // lane i <- i-4
            float pre = k3 + (b2 ? vR : vL);
            pre += dpp_mov<0x128>(pre);             // xor8 combine
            // ---- tanh (prescaled) + 1-fma blend ----
            const float e  = __builtin_amdgcn_exp2f(pre);
            const float rc = __builtin_amdgcn_rcpf(e + 1.0f);
            const float gt = fmaf(-2.0f, rc, 1.0f);
            hreg = fmaf(al_own, gt, hpre);
            hbuf[par][woff] = hreg;
            // ---- SLACK: next-step constants ----
            hpre = fmaf(-al_own, hreg, hreg);       // (1-al)*hreg
            hpPrev[0] = hp[0]; hpPrev[1] = hp[1];
            hpPrev[2] = hp[2]; hpPrev[3] = hp[3];
            // ---- barrier: lgkm-only drain (vmcnt once per window, wave 0) ----
            if (wave == 0 && s == 7)
                asm volatile("s_waitcnt vmcnt(0)" ::: "memory");
            asm volatile("s_waitcnt lgkmcnt(0)" ::: "memory");
            __builtin_amdgcn_s_barrier();
        }
    }

    // ---- tail: V[T-2] from hpPrev (h_{T-2}), V[T-1] from final h, flush ----
    if (wave == 0) {
        v2f vt = vwc[0] * hpPrev[0];
        vt = pk_fma(vwc[1], hpPrev[1], vt);
        vt = pk_fma(vwc[2], hpPrev[2], vt);
        vt = pk_fma(vwc[3], hpPrev[3], vt);
        float vs = vt.x + vt.y;
        vs = dpp_add<0xB1>(vs);
        vs = dpp_add<0x4E>(vs);
        float uL = dpp_mov<0x104>(vs);
        float uR = dpp_mov<0x114>(vs);
        vs += b2 ? uR : uL;
        vs = dpp_add<0x128>(vs);
        if (lane == 0) vres[TT - 2] = vb + vs;
    }
    if (wave == 1) {
        const float* hb = &hbuf[1][12 * j];             // h_{T-1}: parity (TT-1)&1 = 1
        const v4f h0 = *(const v4f*)(hb);
        const v4f h1 = *(const v4f*)(hb + 4);
        v2f hp[4] = { (v2f){h0.x, h0.y}, (v2f){h0.z, h0.w},
                      (v2f){h1.x, h1.y}, (v2f){h1.z, h1.w} };
        v2f vt = vwc[0] * hp[0];
        vt = pk_fma(vwc[1], hp[1], vt);
        vt = pk_fma(vwc[2], hp[2], vt);
        vt = pk_fma(vwc[3], hp[3], vt);
        float vs = vt.x + vt.y;
        vs = dpp_add<0xB1>(vs);
        vs = dpp_add<0x4E>(vs);
        float uL = dpp_mov<0x104>(vs);
        float uR = dpp_mov<0x114>(vs);
        vs += b2 ? uR : uL;
        vs = dpp_add<0x128>(vs);
        if (lane == 0) vres[TT - 1] = vb + vs;
    }
    if (j < 8)
        outH[(size_t)b * HH + base + j] = hreg;
    __syncthreads();
#pragma unroll
    for (int i = 0; i < TT / 256; ++i)
        outV[(size_t)(i * 256 + tid) * BB + b] = vres[i * 256 + tid];
}

extern "C" void kernel_launch(void* const* d_in, const int* in_sizes, int n_in,
                              void* d_out, int out_size, void* d_ws, size_t ws_size,
                              hipStream_t stream) {
    const float* X      = (const float*)d_in[0];
    const float* W_in   = (const float*)d_in[1];
    const float* W_hh   = (const float*)d_in[2];
    const float* rbias  = (const float*)d_in[3];
    const float* alpha  = (const float*)d_in[4];
    const float* vW     = (const float*)d_in[5];
    const float* vbias  = (const float*)d_in[6];
    float* out = (float*)d_out;

    vrnn_kernel<<<dim3(BB), dim3(256), 0, stream>>>(X, W_in, W_hh, rbias, alpha, vW, vbias, out);
}